// Round 1
// baseline (2362.928 us; speedup 1.0000x reference)
//
#include <hip/hip_runtime.h>
#include <math.h>

#define NHID 512
typedef unsigned short u16;
typedef __attribute__((ext_vector_type(8))) short short8;
typedef __attribute__((ext_vector_type(16))) float floatx16;

__device__ __forceinline__ unsigned f2b1(float f) {  // fp32 -> bf16 (RNE)
  unsigned u = __float_as_uint(f);
  return (u + 0x7FFFu + ((u >> 16) & 1u)) >> 16;
}
__device__ __forceinline__ unsigned pk2(float a, float b) {
  return f2b1(a) | (f2b1(b) << 16);
}
__device__ __forceinline__ float sigf(float x) { return 1.0f / (1.0f + expf(-x)); }

__device__ __forceinline__ void gload16(const uint4* g, uint4* l) {
  __builtin_amdgcn_global_load_lds(
      (const __attribute__((address_space(1))) unsigned int*)g,
      (__attribute__((address_space(3))) unsigned int*)l, 16, 0, 0);
}

// ---------------------------------------------------------------------------
// weight transform: fp32 row-major W[3*512][Kw] -> bf16 fragment-major tiles
// unit u = (((cb*3+g)*nch + ch)*8 + g8)*64 + col  holds W[g*512+cb*64+col][ch*64+g8*8 .. +8]
// ---------------------------------------------------------------------------
__global__ void wtransform(const float* __restrict__ W, uint4* __restrict__ Wt,
                           int Kw, int nch) {
  int u = blockIdx.x * 256 + threadIdx.x;
  int total = 8 * 3 * nch * 512;
  if (u >= total) return;
  int col = u & 63;
  int g8 = (u >> 6) & 7;
  int ch = (u >> 9) % nch;
  int t3 = (u >> 9) / nch;
  int g = t3 % 3, cbb = t3 / 3;
  const float* src = W + (size_t)(g * 512 + cbb * 64 + col) * Kw + ch * 64 + g8 * 8;
  float4 f0 = *(const float4*)src;
  float4 f1 = *(const float4*)(src + 4);
  uint4 v = {pk2(f0.x, f0.y), pk2(f0.z, f0.w), pk2(f1.x, f1.y), pk2(f1.z, f1.w)};
  Wt[u] = v;
}

// ---------------------------------------------------------------------------
// copy h -> out (full N*512), float4 grid-stride
// ---------------------------------------------------------------------------
__global__ void copy_h(const float4* __restrict__ src, float4* __restrict__ dst,
                       int n4) {
  int i = blockIdx.x * 256 + threadIdx.x;
  int stride = gridDim.x * 256;
  for (; i < n4; i += stride) dst[i] = src[i];
}

// ---------------------------------------------------------------------------
// prep: loss partials, last-duplicate compaction, gru_in->A_in (bf16),
// h gather->A_h (bf16). One wave (64 lanes = 64 d's) per obs row.
// ---------------------------------------------------------------------------
__global__ void prep_kernel(const float* __restrict__ p,
                            const float* __restrict__ X,
                            const float* __restrict__ Mm,
                            const int* __restrict__ iobs,
                            const float* __restrict__ wprep,
                            const float* __restrict__ bprep,
                            const float* __restrict__ h,
                            u16* __restrict__ A_in, u16* __restrict__ A_h,
                            int* __restrict__ map_i, int* __restrict__ counter,
                            float* __restrict__ partials, int nobs)
{
  __shared__ float sw[4096];
  __shared__ float sb[1024];
  __shared__ int s_cnt[4];
  __shared__ float s_loss[4];
  for (int t = threadIdx.x; t < 4096; t += 256) sw[t] = wprep[t];
  for (int t = threadIdx.x; t < 1024; t += 256) sb[t] = bprep[t];

  const int tid = threadIdx.x;
  const int wave = tid >> 6;
  const int d = tid & 63;
  const int j = blockIdx.x * 4 + wave;
  const bool act = j < nobs;

  int i = 0; bool lastf = false;
  float x = 0.f, mean = 0.f, var = 1.f, m = 0.f, err = 0.f, lossp = 0.f;
  if (act) {
    i = iobs[j];
    lastf = (j == nobs - 1) || (iobs[j + 1] != i);
    mean = p[(size_t)i * 128 + d];
    var  = fabsf(p[(size_t)i * 128 + 64 + d]) + 1e-6f;
    x = X[(size_t)j * 64 + d];
    m = Mm[(size_t)j * 64 + d];
    err = (x - mean) * rsqrtf(var);
    lossp = 0.5f * (err * err + logf(var)) * m;
  }
  __syncthreads();   // sw/sb ready

  #pragma unroll
  for (int off = 32; off > 0; off >>= 1) lossp += __shfl_down(lossp, off, 64);
  if (d == 0) { s_loss[wave] = lossp; s_cnt[wave] = (act && lastf) ? 1 : 0; }
  __syncthreads();
  if (tid == 0) {
    int c0 = s_cnt[0], c1 = s_cnt[1], c2 = s_cnt[2], c3 = s_cnt[3];
    int tot = c0 + c1 + c2 + c3;
    int base = tot ? atomicAdd(counter, tot) : 0;
    s_cnt[0] = base; s_cnt[1] = base + c0;
    s_cnt[2] = base + c0 + c1; s_cnt[3] = base + c0 + c1 + c2;
    partials[blockIdx.x] = s_loss[0] + s_loss[1] + s_loss[2] + s_loss[3];
  }
  __syncthreads();

  if (act && lastf) {
    const int slot = s_cnt[wave];
    if (d == 0) map_i[slot] = i;
    // gru_in features -> bf16
    const float* w = sw + d * 64;   // [4][16]
    const float* b = sb + d * 16;
    float gi[16];
    #pragma unroll
    for (int ph = 0; ph < 16; ++ph) {
      float v = x * w[ph] + mean * w[16 + ph] + var * w[32 + ph] + err * w[48 + ph] + b[ph];
      gi[ph] = fmaxf(v, 0.0f) * m;
    }
    uint4* dst = (uint4*)(A_in + (size_t)slot * 1024 + d * 16);
    uint4 v0 = {pk2(gi[0], gi[1]), pk2(gi[2], gi[3]), pk2(gi[4], gi[5]), pk2(gi[6], gi[7])};
    uint4 v1 = {pk2(gi[8], gi[9]), pk2(gi[10], gi[11]), pk2(gi[12], gi[13]), pk2(gi[14], gi[15])};
    dst[0] = v0; dst[1] = v1;
    // h gather -> bf16
    const float4* hp = (const float4*)(h + (size_t)i * NHID + d * 8);
    float4 a = hp[0], bb = hp[1];
    uint4 hv = {pk2(a.x, a.y), pk2(a.z, a.w), pk2(bb.x, bb.y), pk2(bb.z, bb.w)};
    *(uint4*)(A_h + (size_t)slot * 512 + d * 8) = hv;
  }
}

// ---------------------------------------------------------------------------
__global__ void loss_sum(const float* __restrict__ partials, int n,
                         float* __restrict__ loss) {
  float s = 0.f;
  for (int t = threadIdx.x; t < n; t += 256) s += partials[t];
  #pragma unroll
  for (int off = 32; off > 0; off >>= 1) s += __shfl_down(s, off, 64);
  __shared__ float sw4[4];
  if ((threadIdx.x & 63) == 0) sw4[threadIdx.x >> 6] = s;
  __syncthreads();
  if (threadIdx.x == 0) loss[0] = sw4[0] + sw4[1] + sw4[2] + sw4[3];
}

// ---------------------------------------------------------------------------
// MFMA GEMM v2: 128 rows x (64 h-cols x 3 gates) per block.
// 4 waves 2x2, wave tile 64x32 (2 row-tiles), 8 accumulators/wave.
// A fragments: global->VGPR direct (wave-private rows), prefetched 1 chunk ahead.
// B (weights): global_load_lds width-16 into double-buffered 48 KB LDS,
// counted vmcnt (never 0 in steady state) + raw s_barrier.
// ---------------------------------------------------------------------------
__global__ __launch_bounds__(256, 2) void gemm_mfma(
    const u16* __restrict__ A_in, const u16* __restrict__ A_h,
    const uint4* __restrict__ Wt_ih, const uint4* __restrict__ Wt_hh,
    const int* __restrict__ map_i, const int* __restrict__ counter,
    const float* __restrict__ h,
    const float* __restrict__ bih, const float* __restrict__ bhh,
    float* __restrict__ out)
{
  const int ndist = *counter;
  const int j0 = blockIdx.y * 128;
  if (j0 >= ndist) return;
  const int cb = blockIdx.x;        // 0..7 (h-col block of 64)
  const int tid = threadIdx.x;
  const int lane = tid & 63;
  const int wave = tid >> 6;
  const int wrow = wave >> 1, wcol = wave & 1;
  const int l31 = lane & 31, kh = lane >> 5;

  __shared__ uint4 sB[2 * 1536];    // 48 KB double-buffered [gate][g8][col]

  floatx16 aR0 = {}, aR1 = {}, aZ0 = {}, aZ1 = {};
  floatx16 aI0 = {}, aI1 = {}, aH0 = {}, aH1 = {};

  int gr0 = j0 + wrow * 64 + l31;          // row-tile 0
  int gr1 = gr0 + 32;                      // row-tile 1
  if (gr0 >= ndist) gr0 = ndist - 1;
  if (gr1 >= ndist) gr1 = ndist - 1;

  uint4 aC0[4], aC1[4], aN0[4], aN1[4];

#define STAGE(CH)                                                             \
  {                                                                           \
    const uint4* Wt; int nch, cl;                                             \
    if ((CH) < 16) { Wt = Wt_ih; nch = 16; cl = (CH); }                       \
    else           { Wt = Wt_hh; nch = 8;  cl = (CH) - 16; }                  \
    uint4* dst = sB + ((CH) & 1) * 1536;                                      \
    _Pragma("unroll") for (int pp = 0; pp < 6; ++pp) {                        \
      int idx = pp * 256 + tid;                                               \
      int g = idx >> 9, rem = idx & 511;                                      \
      gload16(Wt + ((size_t)((cb * 3 + g) * nch + cl) << 9) + rem, dst + idx);\
    }                                                                         \
  }

#define ALOAD(CH, R0, R1)                                                     \
  {                                                                           \
    const u16* Ab; int Ks, cl;                                                \
    if ((CH) < 16) { Ab = A_in; Ks = 1024; cl = (CH); }                       \
    else           { Ab = A_h; Ks = 512;  cl = (CH) - 16; }                   \
    const u16* p0 = Ab + (size_t)gr0 * Ks + cl * 64 + kh * 8;                 \
    const u16* p1 = Ab + (size_t)gr1 * Ks + cl * 64 + kh * 8;                 \
    _Pragma("unroll") for (int s = 0; s < 4; ++s) {                           \
      R0[s] = *(const uint4*)(p0 + s * 16);                                   \
      R1[s] = *(const uint4*)(p1 + s * 16);                                   \
    }                                                                         \
  }

#define KSTEPS(N0, N1)                                                        \
  _Pragma("unroll") for (int s = 0; s < 4; ++s) {                             \
    int u = (s * 2 + kh) * 64 + wcol * 32 + l31;                              \
    uint4 b0 = sBc[u], b1 = sBc[512 + u], b2 = sBc[1024 + u];                 \
    short8 f0 = __builtin_bit_cast(short8, b0);                               \
    short8 f1 = __builtin_bit_cast(short8, b1);                               \
    short8 f2 = __builtin_bit_cast(short8, b2);                               \
    short8 x0 = __builtin_bit_cast(short8, aC0[s]);                           \
    short8 x1 = __builtin_bit_cast(short8, aC1[s]);                           \
    aR0 = __builtin_amdgcn_mfma_f32_32x32x16_bf16(x0, f0, aR0, 0, 0, 0);      \
    aR1 = __builtin_amdgcn_mfma_f32_32x32x16_bf16(x1, f0, aR1, 0, 0, 0);      \
    aZ0 = __builtin_amdgcn_mfma_f32_32x32x16_bf16(x0, f1, aZ0, 0, 0, 0);      \
    aZ1 = __builtin_amdgcn_mfma_f32_32x32x16_bf16(x1, f1, aZ1, 0, 0, 0);      \
    N0  = __builtin_amdgcn_mfma_f32_32x32x16_bf16(x0, f2, N0, 0, 0, 0);       \
    N1  = __builtin_amdgcn_mfma_f32_32x32x16_bf16(x1, f2, N1, 0, 0, 0);       \
  }

  // prologue: A[0] -> regs first, then stage S[0] (order matters for vmcnt math)
  ALOAD(0, aC0, aC1)
  STAGE(0)

  for (int ch = 0; ch < 24; ++ch) {
    if (ch < 23) STAGE(ch + 1)
    // wait for S[ch] only: ops issued after it = 8 A-loads (prev iter) + 6 stage
    if (ch == 0)       asm volatile("s_waitcnt vmcnt(6)" ::: "memory");
    else if (ch == 23) asm volatile("s_waitcnt vmcnt(8)" ::: "memory");
    else               asm volatile("s_waitcnt vmcnt(14)" ::: "memory");
    __builtin_amdgcn_s_barrier();
    asm volatile("" ::: "memory");

    if (ch < 23) ALOAD(ch + 1, aN0, aN1)

    const uint4* sBc = sB + (ch & 1) * 1536;
    if (ch < 16) { KSTEPS(aI0, aI1) } else { KSTEPS(aH0, aH1) }

    asm volatile("" ::: "memory");
    __builtin_amdgcn_s_barrier();   // all waves done reading buf[ch&1]
    if (ch < 23) {
      #pragma unroll
      for (int s = 0; s < 4; ++s) { aC0[s] = aN0[s]; aC1[s] = aN1[s]; }
    }
  }

  // epilogue: gates + scatter (compacted rows are unique i's)
  const int col = cb * 64 + wcol * 32 + l31;
  const float biR = bih[col], biZ = bih[512 + col], biN = bih[1024 + col];
  const float bhR = bhh[col], bhZ = bhh[512 + col], bhN = bhh[1024 + col];

#define EPI(R, Z, I, H, RBASE)                                                \
  _Pragma("unroll") for (int r = 0; r < 16; ++r) {                            \
    int rowl = (r & 3) + 8 * (r >> 2) + 4 * kh;                               \
    int jg = (RBASE) + rowl;                                                  \
    if (jg < ndist) {                                                         \
      int i = map_i[jg];                                                      \
      float hv = h[(size_t)i * NHID + col];                                   \
      float rr = sigf(R[r] + biR + bhR);                                      \
      float zz = sigf(Z[r] + biZ + bhZ);                                      \
      float nn = tanhf(I[r] + biN + rr * (H[r] + bhN));                       \
      out[(size_t)i * NHID + col] = (1.0f - zz) * nn + zz * hv;               \
    }                                                                         \
  }

  EPI(aR0, aZ0, aI0, aH0, j0 + wrow * 64)
  EPI(aR1, aZ1, aI1, aH1, j0 + wrow * 64 + 32)

#undef STAGE
#undef ALOAD
#undef KSTEPS
#undef EPI
}

// ---------------------------------------------------------------------------
extern "C" void kernel_launch(void* const* d_in, const int* in_sizes, int n_in,
                              void* d_out, int out_size, void* d_ws, size_t ws_size,
                              hipStream_t stream) {
  const float* h     = (const float*)d_in[0];
  const float* p     = (const float*)d_in[1];
  const float* X     = (const float*)d_in[2];
  const float* Mm    = (const float*)d_in[3];
  const int*   iobs  = (const int*)d_in[4];
  const float* wprep = (const float*)d_in[5];
  const float* bprep = (const float*)d_in[6];
  const float* Wih   = (const float*)d_in[7];
  const float* Whh   = (const float*)d_in[8];
  const float* bih   = (const float*)d_in[9];
  const float* bhh   = (const float*)d_in[10];

  const int N    = in_sizes[0] / NHID;
  const int nobs = in_sizes[4];
  float* out = (float*)d_out;
  float* loss = out + (size_t)N * NHID;

  // workspace layout (bytes)
  char* ws = (char*)d_ws;
  int*   counter  = (int*)ws;                                   // 4 B
  int*   map_i    = (int*)(ws + 1024);                          // nobs * 4
  float* partials = (float*)(ws + (256 << 10));                 // nblocks * 4
  u16*   A_in     = (u16*)(ws + (1 << 20));                     // nobs*1024*2
  u16*   A_h      = (u16*)((char*)A_in + (size_t)nobs * 2048);  // nobs*512*2
  uint4* Wt_ih    = (uint4*)((char*)A_h + (size_t)nobs * 1024); // 3 MB
  uint4* Wt_hh    = (uint4*)((char*)Wt_ih + (size_t)3145728);   // 1.5 MB

  hipMemsetAsync(counter, 0, 4, stream);

  copy_h<<<2048, 256, 0, stream>>>((const float4*)h, (float4*)out, N * 128);

  wtransform<<<768, 256, 0, stream>>>(Wih, Wt_ih, 1024, 16);
  wtransform<<<384, 256, 0, stream>>>(Whh, Wt_hh, 512, 8);

  int nblocks = (nobs + 3) / 4;
  prep_kernel<<<nblocks, 256, 0, stream>>>(p, X, Mm, iobs, wprep, bprep, h,
                                           A_in, A_h, map_i, counter, partials, nobs);
  loss_sum<<<1, 256, 0, stream>>>(partials, nblocks, loss);

  dim3 grid(8, (nobs + 127) / 128);
  gemm_mfma<<<grid, 256, 0, stream>>>(A_in, A_h, Wt_ih, Wt_hh, map_i, counter,
                                      h, bih, bhh, out);
}

// Round 2
// 938.739 us; speedup vs baseline: 2.5171x; 2.5171x over previous
//
#include <hip/hip_runtime.h>
#include <math.h>

#define NHID 512
typedef unsigned short u16;
typedef __attribute__((ext_vector_type(8))) short short8;
typedef __attribute__((ext_vector_type(16))) float floatx16;

__device__ __forceinline__ unsigned f2b1(float f) {  // fp32 -> bf16 (RNE)
  unsigned u = __float_as_uint(f);
  return (u + 0x7FFFu + ((u >> 16) & 1u)) >> 16;
}
__device__ __forceinline__ unsigned pk2(float a, float b) {
  return f2b1(a) | (f2b1(b) << 16);
}
__device__ __forceinline__ float sigf(float x) { return 1.0f / (1.0f + expf(-x)); }

__device__ __forceinline__ void gload16(const void* g, void* l) {
  __builtin_amdgcn_global_load_lds(
      (const __attribute__((address_space(1))) unsigned int*)g,
      (__attribute__((address_space(3))) unsigned int*)l, 16, 0, 0);
}

// ---------------------------------------------------------------------------
// weight transform: fp32 row-major W[3*512][Kw] -> bf16 fragment-major tiles
// unit u = (((cb*3+g)*nch + ch)*8 + g8)*64 + col  holds W[g*512+cb*64+col][ch*64+g8*8 .. +8]
// ---------------------------------------------------------------------------
__global__ void wtransform(const float* __restrict__ W, uint4* __restrict__ Wt,
                           int Kw, int nch) {
  int u = blockIdx.x * 256 + threadIdx.x;
  int total = 8 * 3 * nch * 512;
  if (u >= total) return;
  int col = u & 63;
  int g8 = (u >> 6) & 7;
  int ch = (u >> 9) % nch;
  int t3 = (u >> 9) / nch;
  int g = t3 % 3, cbb = t3 / 3;
  const float* src = W + (size_t)(g * 512 + cbb * 64 + col) * Kw + ch * 64 + g8 * 8;
  float4 f0 = *(const float4*)src;
  float4 f1 = *(const float4*)(src + 4);
  uint4 v = {pk2(f0.x, f0.y), pk2(f0.z, f0.w), pk2(f1.x, f1.y), pk2(f1.z, f1.w)};
  Wt[u] = v;
}

// ---------------------------------------------------------------------------
// copy h -> out (full N*512), float4 grid-stride
// ---------------------------------------------------------------------------
__global__ void copy_h(const float4* __restrict__ src, float4* __restrict__ dst,
                       int n4) {
  int i = blockIdx.x * 256 + threadIdx.x;
  int stride = gridDim.x * 256;
  for (; i < n4; i += stride) dst[i] = src[i];
}

// ---------------------------------------------------------------------------
// prep: loss partials, last-duplicate compaction, gru_in->A_in (bf16),
// h gather->A_h (bf16). One wave (64 lanes = 64 d's) per obs row.
// ---------------------------------------------------------------------------
__global__ void prep_kernel(const float* __restrict__ p,
                            const float* __restrict__ X,
                            const float* __restrict__ Mm,
                            const int* __restrict__ iobs,
                            const float* __restrict__ wprep,
                            const float* __restrict__ bprep,
                            const float* __restrict__ h,
                            u16* __restrict__ A_in, u16* __restrict__ A_h,
                            int* __restrict__ map_i, int* __restrict__ counter,
                            float* __restrict__ partials, int nobs)
{
  __shared__ float sw[4096];
  __shared__ float sb[1024];
  __shared__ int s_cnt[4];
  __shared__ float s_loss[4];
  for (int t = threadIdx.x; t < 4096; t += 256) sw[t] = wprep[t];
  for (int t = threadIdx.x; t < 1024; t += 256) sb[t] = bprep[t];

  const int tid = threadIdx.x;
  const int wave = tid >> 6;
  const int d = tid & 63;
  const int j = blockIdx.x * 4 + wave;
  const bool act = j < nobs;

  int i = 0; bool lastf = false;
  float x = 0.f, mean = 0.f, var = 1.f, m = 0.f, err = 0.f, lossp = 0.f;
  if (act) {
    i = iobs[j];
    lastf = (j == nobs - 1) || (iobs[j + 1] != i);
    mean = p[(size_t)i * 128 + d];
    var  = fabsf(p[(size_t)i * 128 + 64 + d]) + 1e-6f;
    x = X[(size_t)j * 64 + d];
    m = Mm[(size_t)j * 64 + d];
    err = (x - mean) * rsqrtf(var);
    lossp = 0.5f * (err * err + logf(var)) * m;
  }
  __syncthreads();   // sw/sb ready

  #pragma unroll
  for (int off = 32; off > 0; off >>= 1) lossp += __shfl_down(lossp, off, 64);
  if (d == 0) { s_loss[wave] = lossp; s_cnt[wave] = (act && lastf) ? 1 : 0; }
  __syncthreads();
  if (tid == 0) {
    int c0 = s_cnt[0], c1 = s_cnt[1], c2 = s_cnt[2], c3 = s_cnt[3];
    int tot = c0 + c1 + c2 + c3;
    int base = tot ? atomicAdd(counter, tot) : 0;
    s_cnt[0] = base; s_cnt[1] = base + c0;
    s_cnt[2] = base + c0 + c1; s_cnt[3] = base + c0 + c1 + c2;
    partials[blockIdx.x] = s_loss[0] + s_loss[1] + s_loss[2] + s_loss[3];
  }
  __syncthreads();

  if (act && lastf) {
    const int slot = s_cnt[wave];
    if (d == 0) map_i[slot] = i;
    // gru_in features -> bf16
    const float* w = sw + d * 64;   // [4][16]
    const float* b = sb + d * 16;
    float gi[16];
    #pragma unroll
    for (int ph = 0; ph < 16; ++ph) {
      float v = x * w[ph] + mean * w[16 + ph] + var * w[32 + ph] + err * w[48 + ph] + b[ph];
      gi[ph] = fmaxf(v, 0.0f) * m;
    }
    uint4* dst = (uint4*)(A_in + (size_t)slot * 1024 + d * 16);
    uint4 v0 = {pk2(gi[0], gi[1]), pk2(gi[2], gi[3]), pk2(gi[4], gi[5]), pk2(gi[6], gi[7])};
    uint4 v1 = {pk2(gi[8], gi[9]), pk2(gi[10], gi[11]), pk2(gi[12], gi[13]), pk2(gi[14], gi[15])};
    dst[0] = v0; dst[1] = v1;
    // h gather -> bf16
    const float4* hp = (const float4*)(h + (size_t)i * NHID + d * 8);
    float4 a = hp[0], bb = hp[1];
    uint4 hv = {pk2(a.x, a.y), pk2(a.z, a.w), pk2(bb.x, bb.y), pk2(bb.z, bb.w)};
    *(uint4*)(A_h + (size_t)slot * 512 + d * 8) = hv;
  }
}

// ---------------------------------------------------------------------------
__global__ void loss_sum(const float* __restrict__ partials, int n,
                         float* __restrict__ loss) {
  float s = 0.f;
  for (int t = threadIdx.x; t < n; t += 256) s += partials[t];
  #pragma unroll
  for (int off = 32; off > 0; off >>= 1) s += __shfl_down(s, off, 64);
  __shared__ float sw4[4];
  if ((threadIdx.x & 63) == 0) sw4[threadIdx.x >> 6] = s;
  __syncthreads();
  if (threadIdx.x == 0) loss[0] = sw4[0] + sw4[1] + sw4[2] + sw4[3];
}

// ---------------------------------------------------------------------------
// MFMA GEMM v3: v0 geometry (64 rows x 64 h-cols x 3 gates, 4 waves 2x2,
// wave tile 32x32 per gate, acc = 4 x floatx16).
// B fragments: global->VGPR direct (weights are L2/L3-resident, 4.5 MB).
// A: global_load_lds (fragment-major gather) into double-buffered 2x8KB sA,
// counted vmcnt (steady state 14 = 12 B-loads + 2 stage ops), raw s_barrier.
// XCD swizzle: the 8 cb-blocks of one row-group share an XCD's L2.
// ---------------------------------------------------------------------------
__global__ __launch_bounds__(256, 2) void gemm_mfma(
    const u16* __restrict__ A_in, const u16* __restrict__ A_h,
    const uint4* __restrict__ Wt_ih, const uint4* __restrict__ Wt_hh,
    const int* __restrict__ map_i, const int* __restrict__ counter,
    const float* __restrict__ h,
    const float* __restrict__ bih, const float* __restrict__ bhh,
    float* __restrict__ out)
{
  const int ndist = *counter;
  const int bid = blockIdx.x;
  const int jb = (bid & 7) + 8 * (bid >> 6);   // row-group: same XCD for all cb
  const int cb = (bid >> 3) & 7;               // h-col block of 64
  const int j0 = jb * 64;
  if (j0 >= ndist) return;

  const int tid = threadIdx.x;
  const int lane = tid & 63;
  const int wave = tid >> 6;
  const int wrow = wave >> 1, wcol = wave & 1;
  const int l31 = lane & 31, kh = lane >> 5;
  const int arow = l31 + 32 * wrow;
  const int bcol = l31 + 32 * wcol;

  __shared__ uint4 sA[2 * 512];     // 16 KB double-buffered, [buf][g8][row]

  floatx16 accR = {}, accZ = {}, accI = {}, accH = {};

  int grs = j0 + lane;              // this lane's staged row (clamped)
  if (grs >= ndist) grs = ndist - 1;

#define STAGE(CH)                                                             \
  {                                                                           \
    const u16* Ab; int Ks, cl;                                                \
    if ((CH) < 16) { Ab = A_in; Ks = 1024; cl = (CH); }                       \
    else           { Ab = A_h;  Ks = 512;  cl = (CH) - 16; }                  \
    _Pragma("unroll") for (int pp = 0; pp < 2; ++pp) {                        \
      int g8 = wave + pp * 4;                                                 \
      gload16(Ab + (size_t)grs * Ks + cl * 64 + g8 * 8,                       \
              sA + ((CH) & 1) * 512 + g8 * 64);                               \
    }                                                                         \
  }

#define CHUNK(CH, ACC3, LAST)                                                 \
  {                                                                           \
    const uint4* Bp; size_t gs;                                               \
    if ((CH) < 16) { Bp = Wt_ih + ((size_t)(cb * 3) * 16 + (CH)) * 512;       \
                     gs = 16 * 512; }                                         \
    else           { Bp = Wt_hh + ((size_t)(cb * 3) * 8 + (CH) - 16) * 512;   \
                     gs = 8 * 512; }                                          \
    uint4 b0[4], b1[4], b2[4];                                                \
    _Pragma("unroll") for (int s = 0; s < 4; ++s) {                           \
      int u = (s * 2 + kh) * 64 + bcol;                                       \
      b0[s] = Bp[u]; b1[s] = Bp[gs + u]; b2[s] = Bp[2 * gs + u];              \
    }                                                                         \
    if (!(LAST)) { STAGE((CH) + 1) }                                          \
    if (!(LAST)) asm volatile("s_waitcnt vmcnt(14)" ::: "memory");            \
    else         asm volatile("s_waitcnt vmcnt(12)" ::: "memory");            \
    __builtin_amdgcn_s_barrier();                                             \
    asm volatile("" ::: "memory");                                            \
    const uint4* sAc = sA + ((CH) & 1) * 512;                                 \
    uint4 av[4];                                                              \
    _Pragma("unroll") for (int s = 0; s < 4; ++s)                             \
      av[s] = sAc[(s * 2 + kh) * 64 + arow];                                  \
    _Pragma("unroll") for (int s = 0; s < 4; ++s) {                           \
      short8 aF = __builtin_bit_cast(short8, av[s]);                          \
      accR = __builtin_amdgcn_mfma_f32_32x32x16_bf16(                         \
          aF, __builtin_bit_cast(short8, b0[s]), accR, 0, 0, 0);              \
      accZ = __builtin_amdgcn_mfma_f32_32x32x16_bf16(                         \
          aF, __builtin_bit_cast(short8, b1[s]), accZ, 0, 0, 0);              \
      ACC3 = __builtin_amdgcn_mfma_f32_32x32x16_bf16(                         \
          aF, __builtin_bit_cast(short8, b2[s]), ACC3, 0, 0, 0);              \
    }                                                                         \
    asm volatile("" ::: "memory");                                            \
    __builtin_amdgcn_s_barrier();                                             \
  }

  // prologue: stage chunk 0
  STAGE(0)

  // phase 1: gru_in @ Wih^T  (K = 1024, chunks 0..15)
  for (int ch = 0; ch < 16; ++ch) { CHUNK(ch, accI, 0) }
  // phase 2: h_prev @ Whh^T  (K = 512, chunks 16..23)
  for (int ch = 16; ch < 24; ++ch) { CHUNK(ch, accH, (ch == 23)) }

  // epilogue: gates + scatter (compacted rows are unique i's)
  const int col = cb * 64 + 32 * wcol + l31;
  const float biR = bih[col], biZ = bih[512 + col], biN = bih[1024 + col];
  const float bhR = bhh[col], bhZ = bhh[512 + col], bhN = bhh[1024 + col];
  #pragma unroll
  for (int r = 0; r < 16; ++r) {
    int rowl = (r & 3) + 8 * (r >> 2) + 4 * kh + 32 * wrow;
    int jg = j0 + rowl;
    if (jg >= ndist) continue;
    int i = map_i[jg];
    float hv = h[(size_t)i * NHID + col];
    float rr = sigf(accR[r] + biR + bhR);
    float zz = sigf(accZ[r] + biZ + bhZ);
    float nn = tanhf(accI[r] + biN + rr * (accH[r] + bhN));
    out[(size_t)i * NHID + col] = (1.0f - zz) * nn + zz * hv;
  }
#undef STAGE
#undef CHUNK
}

// ---------------------------------------------------------------------------
extern "C" void kernel_launch(void* const* d_in, const int* in_sizes, int n_in,
                              void* d_out, int out_size, void* d_ws, size_t ws_size,
                              hipStream_t stream) {
  const float* h     = (const float*)d_in[0];
  const float* p     = (const float*)d_in[1];
  const float* X     = (const float*)d_in[2];
  const float* Mm    = (const float*)d_in[3];
  const int*   iobs  = (const int*)d_in[4];
  const float* wprep = (const float*)d_in[5];
  const float* bprep = (const float*)d_in[6];
  const float* Wih   = (const float*)d_in[7];
  const float* Whh   = (const float*)d_in[8];
  const float* bih   = (const float*)d_in[9];
  const float* bhh   = (const float*)d_in[10];

  const int N    = in_sizes[0] / NHID;
  const int nobs = in_sizes[4];
  float* out = (float*)d_out;
  float* loss = out + (size_t)N * NHID;

  // workspace layout (bytes)
  char* ws = (char*)d_ws;
  int*   counter  = (int*)ws;                                   // 4 B
  int*   map_i    = (int*)(ws + 1024);                          // nobs * 4
  float* partials = (float*)(ws + (256 << 10));                 // nblocks * 4
  u16*   A_in     = (u16*)(ws + (1 << 20));                     // nobs*1024*2
  u16*   A_h      = (u16*)((char*)A_in + (size_t)nobs * 2048);  // nobs*512*2
  uint4* Wt_ih    = (uint4*)((char*)A_h + (size_t)nobs * 1024); // 3 MB
  uint4* Wt_hh    = (uint4*)((char*)Wt_ih + (size_t)3145728);   // 1.5 MB

  hipMemsetAsync(counter, 0, 4, stream);

  copy_h<<<2048, 256, 0, stream>>>((const float4*)h, (float4*)out, N * 128);

  wtransform<<<768, 256, 0, stream>>>(Wih, Wt_ih, 1024, 16);
  wtransform<<<384, 256, 0, stream>>>(Whh, Wt_hh, 512, 8);

  int nblocks = (nobs + 3) / 4;
  prep_kernel<<<nblocks, 256, 0, stream>>>(p, X, Mm, iobs, wprep, bprep, h,
                                           A_in, A_h, map_i, counter, partials, nobs);
  loss_sum<<<1, 256, 0, stream>>>(partials, nblocks, loss);

  int njb = (nobs + 63) / 64;
  int nhi = (njb + 7) / 8;
  gemm_mfma<<<64 * nhi, 256, 0, stream>>>(A_in, A_h, Wt_ih, Wt_hh, map_i,
                                          counter, h, bih, bhh, out);
}

// Round 3
// 914.619 us; speedup vs baseline: 2.5835x; 1.0264x over previous
//
#include <hip/hip_runtime.h>
#include <math.h>

#define NHID 512
typedef unsigned short u16;
typedef __attribute__((ext_vector_type(8))) short short8;
typedef __attribute__((ext_vector_type(16))) float floatx16;

__device__ __forceinline__ unsigned f2b1(float f) {  // fp32 -> bf16 (RNE)
  unsigned u = __float_as_uint(f);
  return (u + 0x7FFFu + ((u >> 16) & 1u)) >> 16;
}
__device__ __forceinline__ unsigned pk2(float a, float b) {
  return f2b1(a) | (f2b1(b) << 16);
}
__device__ __forceinline__ float sigf(float x) { return 1.0f / (1.0f + expf(-x)); }

// ---------------------------------------------------------------------------
// weight transform body: fp32 row-major W[3*512][Kw] -> bf16 fragment-major
// unit u = (((cb*3+g)*nch + ch)*8 + g8)*64 + col holds W[g*512+cb*64+col][ch*64+g8*8 ..+8]
// ---------------------------------------------------------------------------
__device__ __forceinline__ void wt_body(const float* __restrict__ W,
                                        uint4* __restrict__ Wt, int Kw,
                                        int nch, int u) {
  int col = u & 63;
  int g8 = (u >> 6) & 7;
  int ch = (u >> 9) % nch;
  int t3 = (u >> 9) / nch;
  int g = t3 % 3, cbb = t3 / 3;
  const float* src = W + (size_t)(g * 512 + cbb * 64 + col) * Kw + ch * 64 + g8 * 8;
  float4 f0 = *(const float4*)src;
  float4 f1 = *(const float4*)(src + 4);
  uint4 v = {pk2(f0.x, f0.y), pk2(f0.z, f0.w), pk2(f1.x, f1.y), pk2(f1.z, f1.w)};
  Wt[u] = v;
}

// ---------------------------------------------------------------------------
// fused housekeeping: wtransform(ih) | wtransform(hh) | counter clear | copy h->out
// ---------------------------------------------------------------------------
__global__ void housekeeping(const float* __restrict__ Wih, uint4* __restrict__ Wt_ih,
                             const float* __restrict__ Whh, uint4* __restrict__ Wt_hh,
                             const float4* __restrict__ h4, float4* __restrict__ out4,
                             int n4, int* __restrict__ counter) {
  int b = blockIdx.x;
  if (b < 768) {                       // 768*256 = 196608 = 8*3*16*512 units
    wt_body(Wih, Wt_ih, 1024, 16, b * 256 + (int)threadIdx.x);
    return;
  }
  if (b < 1152) {                      // 384*256 = 98304 = 8*3*8*512 units
    wt_body(Whh, Wt_hh, 512, 8, (b - 768) * 256 + (int)threadIdx.x);
    return;
  }
  if (b == 1152) {
    if (threadIdx.x == 0) *counter = 0;
    return;
  }
  int i = (b - 1153) * 256 + threadIdx.x;
  for (; i < n4; i += 2048 * 256) out4[i] = h4[i];
}

// ---------------------------------------------------------------------------
// prep: loss partials, last-duplicate compaction, gru_in + h-gather written
// DIRECTLY in MFMA fragment-major layout:
//   A_fm[((g*16 + ch)*8 + g8)*64 + row]  (uint4, 16B = 8 bf16, k = ch*64+g8*8)
//   H_fm[((g*8  + ch)*8 + g8)*64 + row]
// where g = slot>>6, row = slot&63. One wave (64 lanes = 64 d's) per obs row.
// ---------------------------------------------------------------------------
__global__ void prep_kernel(const float* __restrict__ p,
                            const float* __restrict__ X,
                            const float* __restrict__ Mm,
                            const int* __restrict__ iobs,
                            const float* __restrict__ wprep,
                            const float* __restrict__ bprep,
                            const float* __restrict__ h,
                            uint4* __restrict__ A_fm, uint4* __restrict__ H_fm,
                            int* __restrict__ map_i, int* __restrict__ counter,
                            float* __restrict__ partials, int nobs)
{
  __shared__ float sw[4096];
  __shared__ float sb[1024];
  __shared__ int s_cnt[4];
  __shared__ float s_loss[4];
  for (int t = threadIdx.x; t < 4096; t += 256) sw[t] = wprep[t];
  for (int t = threadIdx.x; t < 1024; t += 256) sb[t] = bprep[t];

  const int tid = threadIdx.x;
  const int wave = tid >> 6;
  const int d = tid & 63;
  const int j = blockIdx.x * 4 + wave;
  const bool act = j < nobs;

  int i = 0; bool lastf = false;
  float x = 0.f, mean = 0.f, var = 1.f, m = 0.f, err = 0.f, lossp = 0.f;
  if (act) {
    i = iobs[j];
    lastf = (j == nobs - 1) || (iobs[j + 1] != i);
    mean = p[(size_t)i * 128 + d];
    var  = fabsf(p[(size_t)i * 128 + 64 + d]) + 1e-6f;
    x = X[(size_t)j * 64 + d];
    m = Mm[(size_t)j * 64 + d];
    err = (x - mean) * rsqrtf(var);
    lossp = 0.5f * (err * err + logf(var)) * m;
  }
  __syncthreads();   // sw/sb ready

  #pragma unroll
  for (int off = 32; off > 0; off >>= 1) lossp += __shfl_down(lossp, off, 64);
  if (d == 0) { s_loss[wave] = lossp; s_cnt[wave] = (act && lastf) ? 1 : 0; }
  __syncthreads();
  if (tid == 0) {
    int c0 = s_cnt[0], c1 = s_cnt[1], c2 = s_cnt[2], c3 = s_cnt[3];
    int tot = c0 + c1 + c2 + c3;
    int base = tot ? atomicAdd(counter, tot) : 0;
    s_cnt[0] = base; s_cnt[1] = base + c0;
    s_cnt[2] = base + c0 + c1; s_cnt[3] = base + c0 + c1 + c2;
    partials[blockIdx.x] = s_loss[0] + s_loss[1] + s_loss[2] + s_loss[3];
  }
  __syncthreads();

  if (act && lastf) {
    const int slot = s_cnt[wave];
    if (d == 0) map_i[slot] = i;
    const int g = slot >> 6, row = slot & 63;
    // gru_in features -> bf16 (k-range of this lane: d*16 .. d*16+15)
    const float* w = sw + d * 64;   // [4][16]
    const float* b = sb + d * 16;
    float gi[16];
    #pragma unroll
    for (int ph = 0; ph < 16; ++ph) {
      float v = x * w[ph] + mean * w[16 + ph] + var * w[32 + ph] + err * w[48 + ph] + b[ph];
      gi[ph] = fmaxf(v, 0.0f) * m;
    }
    uint4 v0 = {pk2(gi[0], gi[1]), pk2(gi[2], gi[3]), pk2(gi[4], gi[5]), pk2(gi[6], gi[7])};
    uint4 v1 = {pk2(gi[8], gi[9]), pk2(gi[10], gi[11]), pk2(gi[12], gi[13]), pk2(gi[14], gi[15])};
    // fragment-major: ch = d>>2, g8 = (d&3)*2 + {0,1}
    uint4* fmA = A_fm + ((size_t)((g * 16 + (d >> 2)) * 8 + (d & 3) * 2)) * 64 + row;
    fmA[0]  = v0;
    fmA[64] = v1;
    // h gather -> bf16 (k-range d*8 .. d*8+7): ch = d>>3, g8 = d&7
    const float4* hp = (const float4*)(h + (size_t)i * NHID + d * 8);
    float4 a = hp[0], bb = hp[1];
    uint4 hv = {pk2(a.x, a.y), pk2(a.z, a.w), pk2(bb.x, bb.y), pk2(bb.z, bb.w)};
    H_fm[((size_t)((g * 8 + (d >> 3)) * 8 + (d & 7))) * 64 + row] = hv;
  }
}

// ---------------------------------------------------------------------------
// MFMA GEMM v4: barrier-free, LDS-free. 64 rows x 64 h-cols x 3 gates per
// block, 4 waves 2x2, wave tile 32x32 per gate, acc = 4 x floatx16.
// A fragments: coalesced direct loads from fragment-major A_fm/H_fm.
// B fragments: coalesced direct loads from Wt (L2/L3-resident).
// Block 0: loss reduction. XCD swizzle keeps all 8 cb of a jb on one XCD.
// ---------------------------------------------------------------------------
__global__ __launch_bounds__(256, 3) void gemm_mfma(
    const uint4* __restrict__ A_fm, const uint4* __restrict__ H_fm,
    const uint4* __restrict__ Wt_ih, const uint4* __restrict__ Wt_hh,
    const int* __restrict__ map_i, const int* __restrict__ counter,
    const float* __restrict__ h,
    const float* __restrict__ bih, const float* __restrict__ bhh,
    const float* __restrict__ partials, int nparts,
    float* __restrict__ out, float* __restrict__ loss)
{
  const int tid = threadIdx.x;
  if (blockIdx.x == 0) {   // fused loss reduction
    float s = 0.f;
    for (int t = tid; t < nparts; t += 256) s += partials[t];
    #pragma unroll
    for (int off = 32; off > 0; off >>= 1) s += __shfl_down(s, off, 64);
    __shared__ float sw4[4];
    if ((tid & 63) == 0) sw4[tid >> 6] = s;
    __syncthreads();
    if (tid == 0) loss[0] = sw4[0] + sw4[1] + sw4[2] + sw4[3];
    return;
  }

  const int ndist = *counter;
  const int bid = blockIdx.x - 1;
  const int jb = (bid & 7) + 8 * (bid >> 6);   // row-group: same XCD for all cb
  const int cb = (bid >> 3) & 7;               // h-col block of 64
  const int j0 = jb * 64;
  if (j0 >= ndist) return;

  const int lane = tid & 63;
  const int wave = tid >> 6;
  const int wrow = wave >> 1, wcol = wave & 1;
  const int l31 = lane & 31, kh = lane >> 5;
  const int arow = l31 + 32 * wrow;
  const int bcol = l31 + 32 * wcol;

  floatx16 accR = {}, accZ = {}, accI = {}, accH = {};

  // phase 1: gru_in @ Wih^T  (K = 1024, 16 chunks of 64)
  for (int cl = 0; cl < 16; ++cl) {
    const uint4* Ap = A_fm + (size_t)(jb * 16 + cl) * 512;     // [g8][row]
    const uint4* Bp = Wt_ih + (size_t)(cb * 48 + cl) * 512;    // gate stride 8192
    #pragma unroll
    for (int s = 0; s < 4; ++s) {
      int u = (s * 2 + kh) * 64;
      uint4 av = Ap[u + arow];
      uint4 b0 = Bp[u + bcol];
      uint4 b1 = Bp[8192 + u + bcol];
      uint4 b2 = Bp[16384 + u + bcol];
      short8 aF = __builtin_bit_cast(short8, av);
      accR = __builtin_amdgcn_mfma_f32_32x32x16_bf16(
          aF, __builtin_bit_cast(short8, b0), accR, 0, 0, 0);
      accZ = __builtin_amdgcn_mfma_f32_32x32x16_bf16(
          aF, __builtin_bit_cast(short8, b1), accZ, 0, 0, 0);
      accI = __builtin_amdgcn_mfma_f32_32x32x16_bf16(
          aF, __builtin_bit_cast(short8, b2), accI, 0, 0, 0);
    }
  }
  // phase 2: h_prev @ Whh^T  (K = 512, 8 chunks of 64)
  for (int cl = 0; cl < 8; ++cl) {
    const uint4* Ap = H_fm + (size_t)(jb * 8 + cl) * 512;
    const uint4* Bp = Wt_hh + (size_t)(cb * 24 + cl) * 512;    // gate stride 4096
    #pragma unroll
    for (int s = 0; s < 4; ++s) {
      int u = (s * 2 + kh) * 64;
      uint4 av = Ap[u + arow];
      uint4 b0 = Bp[u + bcol];
      uint4 b1 = Bp[4096 + u + bcol];
      uint4 b2 = Bp[8192 + u + bcol];
      short8 aF = __builtin_bit_cast(short8, av);
      accR = __builtin_amdgcn_mfma_f32_32x32x16_bf16(
          aF, __builtin_bit_cast(short8, b0), accR, 0, 0, 0);
      accZ = __builtin_amdgcn_mfma_f32_32x32x16_bf16(
          aF, __builtin_bit_cast(short8, b1), accZ, 0, 0, 0);
      accH = __builtin_amdgcn_mfma_f32_32x32x16_bf16(
          aF, __builtin_bit_cast(short8, b2), accH, 0, 0, 0);
    }
  }

  // epilogue: gates + scatter (compacted rows are unique i's)
  const int col = cb * 64 + 32 * wcol + l31;
  const float biR = bih[col], biZ = bih[512 + col], biN = bih[1024 + col];
  const float bhR = bhh[col], bhZ = bhh[512 + col], bhN = bhh[1024 + col];
  #pragma unroll
  for (int r = 0; r < 16; ++r) {
    int rowl = (r & 3) + 8 * (r >> 2) + 4 * kh + 32 * wrow;
    int jg = j0 + rowl;
    if (jg >= ndist) continue;
    int i = map_i[jg];
    float hv = h[(size_t)i * NHID + col];
    float rr = sigf(accR[r] + biR + bhR);
    float zz = sigf(accZ[r] + biZ + bhZ);
    float nn = tanhf(accI[r] + biN + rr * (accH[r] + bhN));
    out[(size_t)i * NHID + col] = (1.0f - zz) * nn + zz * hv;
  }
}

// ---------------------------------------------------------------------------
extern "C" void kernel_launch(void* const* d_in, const int* in_sizes, int n_in,
                              void* d_out, int out_size, void* d_ws, size_t ws_size,
                              hipStream_t stream) {
  const float* h     = (const float*)d_in[0];
  const float* p     = (const float*)d_in[1];
  const float* X     = (const float*)d_in[2];
  const float* Mm    = (const float*)d_in[3];
  const int*   iobs  = (const int*)d_in[4];
  const float* wprep = (const float*)d_in[5];
  const float* bprep = (const float*)d_in[6];
  const float* Wih   = (const float*)d_in[7];
  const float* Whh   = (const float*)d_in[8];
  const float* bih   = (const float*)d_in[9];
  const float* bhh   = (const float*)d_in[10];

  const int N    = in_sizes[0] / NHID;
  const int nobs = in_sizes[4];
  float* out = (float*)d_out;
  float* loss = out + (size_t)N * NHID;

  const int ngmax = (nobs + 63) / 64;            // worst-case row-groups

  // workspace layout (bytes)
  char* ws = (char*)d_ws;
  int*   counter  = (int*)ws;                                   // 4 B
  int*   map_i    = (int*)(ws + 1024);                          // nobs * 4
  float* partials = (float*)(ws + (256 << 10));                 // nblocks * 4
  uint4* A_fm     = (uint4*)(ws + (1 << 20));                   // ngmax * 128 KB
  uint4* H_fm     = (uint4*)((char*)A_fm + (size_t)ngmax * 131072); // ngmax * 64 KB
  uint4* Wt_ih    = (uint4*)((char*)H_fm + (size_t)ngmax * 65536);  // 3 MB
  uint4* Wt_hh    = (uint4*)((char*)Wt_ih + (size_t)3145728);       // 1.5 MB

  // K1: wtransform x2 + counter clear + copy h->out   (3201 blocks)
  housekeeping<<<3201, 256, 0, stream>>>(Wih, Wt_ih, Whh, Wt_hh,
                                         (const float4*)h, (float4*)out,
                                         N * 128, counter);

  // K2: prep (writes fragment-major A/H, partial losses, compaction map)
  int nblocks = (nobs + 3) / 4;
  prep_kernel<<<nblocks, 256, 0, stream>>>(p, X, Mm, iobs, wprep, bprep, h,
                                           A_fm, H_fm, map_i, counter, partials, nobs);

  // K3: gemm + gates + scatter; block 0 reduces the loss
  int nhi = (ngmax + 7) / 8;
  gemm_mfma<<<1 + 64 * nhi, 256, 0, stream>>>(A_fm, H_fm, Wt_ih, Wt_hh, map_i,
                                              counter, h, bih, bhh,
                                              partials, nblocks, out, loss);
}